// Round 33
// baseline (2848.496 us; speedup 1.0000x reference)
//
#include <hip/hip_runtime.h>

#define NN 100000
#define EE 400000
#define GG 4000
#define EMB 300
#define EMB2 600
#define LL 5
#define BN_EPS 1e-5f
#define BUF_BYTES 120000000ull
#define SCAN_NB 98
#define WSET 1597440ull
#define NCOPY 16

// barrier with LDS-only drain: leaves global prefetch loads in flight (T4)
#define BAR_LGKM() asm volatile("s_waitcnt lgkmcnt(0)\ns_barrier" ::: "memory")

typedef __attribute__((ext_vector_type(8))) short bf16x8;
typedef __attribute__((ext_vector_type(4))) short bf16x4;
typedef __attribute__((ext_vector_type(2))) short bf16x2;
typedef __attribute__((ext_vector_type(4))) float f32x4;

__device__ __constant__ int c_atom_off[9] = {0,119,123,135,147,157,163,169,171};

static __device__ __forceinline__ float u16tof(unsigned short u) {
    return __uint_as_float(((unsigned int)u) << 16);
}
static __device__ __forceinline__ unsigned short ftobf(float f) {
    unsigned int u = __float_as_uint(f);
    unsigned int r = 0x7fffu + ((u >> 16) & 1u);
    return (unsigned short)((u + r) >> 16);
}
static __device__ __forceinline__ int geti(const void* p, int f64, long long i) {
    return f64 ? (int)((const long long*)p)[i] : ((const int*)p)[i];
}
static __device__ __forceinline__ f32x4 mfma16(bf16x8 a, bf16x8 b, f32x4 c) {
    return __builtin_amdgcn_mfma_f32_16x16x32_bf16(a, b, c, 0, 0, 0);
}

__global__ void k_detect(const int* __restrict__ ei, int* __restrict__ flag) {
    __shared__ int cnt;
    if (threadIdx.x == 0) cnt = 0;
    __syncthreads();
    int z = 0;
    for (int i = threadIdx.x; i < 1024; i += 256)
        if (ei[2 * i + 1] == 0) z++;
    atomicAdd(&cnt, z);
    __syncthreads();
    if (threadIdx.x == 0) *flag = (cnt > 512) ? 1 : 0;
}

__global__ void k_init(float* __restrict__ sc2, float* __restrict__ sh2) {
    const int c = blockIdx.x * 256 + threadIdx.x;
    if (c < EMB) { sc2[c] = 1.f; sh2[c] = 0.f; }
}

__global__ void k_encode(const void* __restrict__ x, const float* __restrict__ aemb,
                         float* __restrict__ h, const int* __restrict__ flag) {
    __shared__ int xi[4][9];
    const int ty = threadIdx.y, tx = threadIdx.x;
    const int n = blockIdx.x * 4 + ty;
    const int f64 = *flag;
    if (tx < 9) xi[ty][tx] = geti(x, f64, (long long)n * 9 + tx) + c_atom_off[tx];
    __syncthreads();
    if (tx < 75) {
        const int c = tx * 4;
        float s0 = 0.f, s1 = 0.f, s2 = 0.f, s3 = 0.f;
#pragma unroll
        for (int f = 0; f < 9; ++f) {
            const float4 v = *(const float4*)(aemb + (size_t)xi[ty][f] * EMB + c);
            s0 += v.x; s1 += v.y; s2 += v.z; s3 += v.w;
        }
        float4 o; o.x = s0; o.y = s1; o.z = s2; o.w = s3;
        *(float4*)(h + (size_t)n * EMB + c) = o;
    }
}

__global__ void k_deg(const void* __restrict__ ei, int* __restrict__ deg,
                      const int* __restrict__ flag) {
    const int e = blockIdx.x * 256 + threadIdx.x;
    if (e < EE) atomicAdd(&deg[geti(ei, *flag, (long long)EE + e)], 1);
}

__global__ void k_scanA(const int* __restrict__ deg, int* __restrict__ bsum) {
    __shared__ int red[256];
    const int b = blockIdx.x, t = threadIdx.x;
    const int base = b * 1024 + t * 4;
    int s = 0;
#pragma unroll
    for (int e = 0; e < 4; ++e) {
        const int i = base + e;
        if (i < NN) s += deg[i];
    }
    red[t] = s;
    __syncthreads();
    for (int off = 128; off > 0; off >>= 1) {
        if (t < off) red[t] += red[t + off];
        __syncthreads();
    }
    if (t == 0) bsum[b] = red[0];
}

__global__ void k_scanB(const int* __restrict__ bsum, int* __restrict__ bbase,
                        int* __restrict__ rowstart) {
    if (threadIdx.x == 0) {
        int run = 0;
        for (int b = 0; b < SCAN_NB; ++b) { bbase[b] = run; run += bsum[b]; }
        rowstart[NN] = run;
    }
}

__global__ void k_scanC(const int* __restrict__ deg, const int* __restrict__ bbase,
                        int* __restrict__ rowstart, int* __restrict__ cursor) {
    __shared__ int ts[256];
    const int b = blockIdx.x, t = threadIdx.x;
    const int base = b * 1024 + t * 4;
    int loc[4];
    int s = 0;
#pragma unroll
    for (int e = 0; e < 4; ++e) {
        const int i = base + e;
        loc[e] = (i < NN) ? deg[i] : 0;
        s += loc[e];
    }
    ts[t] = s;
    __syncthreads();
    for (int off = 1; off < 256; off <<= 1) {
        const int v = (t >= off) ? ts[t - off] : 0;
        __syncthreads();
        ts[t] += v;
        __syncthreads();
    }
    int run = bbase[b] + ts[t] - s;
#pragma unroll
    for (int e = 0; e < 4; ++e) {
        const int i = base + e;
        if (i < NN) { rowstart[i] = run; cursor[i] = run; run += loc[e]; }
    }
}

__global__ void k_scatter(const void* __restrict__ ei, const void* __restrict__ eattr,
                          int* __restrict__ cursor, int* __restrict__ elist,
                          const int* __restrict__ flag) {
    const int e = blockIdx.x * 256 + threadIdx.x;
    if (e >= EE) return;
    const int f64 = *flag;
    const int src = geti(ei, f64, e);
    const int dst = geti(ei, f64, (long long)EE + e);
    const int b0 = geti(eattr, f64, (long long)e * 3 + 0);
    const int b1 = geti(eattr, f64, (long long)e * 3 + 1);
    const int b2 = geti(eattr, f64, (long long)e * 3 + 2);
    const int pos = atomicAdd(&cursor[dst], 1);
    elist[pos] = src * 64 + b0 * 12 + b1 * 2 + b2;
}

__global__ void k_ebc(const float* __restrict__ bemb, float* __restrict__ ebc) {
    const int cb = blockIdx.x;
    const int tx = threadIdx.x;
    if (tx >= 75) return;
    const int b0 = cb / 12, b1 = (cb / 2) % 6, b2 = cb & 1;
    const int c = tx * 4;
    const float4 v0 = *(const float4*)(bemb + (size_t)b0 * EMB + c);
    const float4 v1 = *(const float4*)(bemb + (size_t)(5 + b1) * EMB + c);
    const float4 v2 = *(const float4*)(bemb + (size_t)(11 + b2) * EMB + c);
    float4 o; o.x = v0.x + v1.x + v2.x; o.y = v0.y + v1.y + v2.y;
    o.z = v0.z + v1.z + v2.z; o.w = v0.w + v1.w + v2.w;
    *(float4*)(ebc + (size_t)cb * EMB + c) = o;
}

// ---- gather: 4 nodes/block, batched edge loads, fused BN2+relu ----
__global__ void k_gather(const int* __restrict__ rowstart, const int* __restrict__ elist,
                         const float* __restrict__ ebc,
                         const float* __restrict__ h, float* __restrict__ z,
                         const float* __restrict__ sc, const float* __restrict__ sh,
                         int dorelu) {
    const int ty = threadIdx.y, tx = threadIdx.x;
    const int n = blockIdx.x * 4 + ty;
    if (tx >= 75) return;
    const int c = tx * 4;
    const float4 s4 = *(const float4*)(sc + c);
    const float4 h4 = *(const float4*)(sh + c);
    const int s = rowstart[n], e = rowstart[n + 1];
    float4 acc;
    {
        float4 v = *(const float4*)(h + (size_t)n * EMB + c);
        v.x = fmaf(v.x, s4.x, h4.x); v.y = fmaf(v.y, s4.y, h4.y);
        v.z = fmaf(v.z, s4.z, h4.z); v.w = fmaf(v.w, s4.w, h4.w);
        if (dorelu) {
            v.x = fmaxf(v.x, 0.f); v.y = fmaxf(v.y, 0.f);
            v.z = fmaxf(v.z, 0.f); v.w = fmaxf(v.w, 0.f);
        }
        acc = v;
    }
    for (int j = s; j < e; j += 4) {
        const int m = e - j;
        int pk[4];
#pragma unroll
        for (int d = 0; d < 4; ++d) pk[d] = (d < m) ? elist[j + d] : 0;
        float4 hv[4], ev[4];
#pragma unroll
        for (int d = 0; d < 4; ++d) {
            if (d < m) {
                const int src = pk[d] >> 6, cb = pk[d] & 63;
                hv[d] = *(const float4*)(h + (size_t)src * EMB + c);
                ev[d] = *(const float4*)(ebc + (size_t)cb * EMB + c);
            }
        }
#pragma unroll
        for (int d = 0; d < 4; ++d) {
            if (d < m) {
                float4 t = hv[d];
                t.x = fmaf(t.x, s4.x, h4.x); t.y = fmaf(t.y, s4.y, h4.y);
                t.z = fmaf(t.z, s4.z, h4.z); t.w = fmaf(t.w, s4.w, h4.w);
                if (dorelu) {
                    t.x = fmaxf(t.x, 0.f); t.y = fmaxf(t.y, 0.f);
                    t.z = fmaxf(t.z, 0.f); t.w = fmaxf(t.w, 0.f);
                }
                acc.x += fmaxf(t.x + ev[d].x, 0.f);
                acc.y += fmaxf(t.y + ev[d].y, 0.f);
                acc.z += fmaxf(t.z + ev[d].z, 0.f);
                acc.w += fmaxf(t.w + ev[d].w, 0.f);
            }
        }
    }
    *(float4*)(z + (size_t)n * EMB + c) = acc;
}

__global__ void k_wconv1(const float* __restrict__ W, unsigned short* __restrict__ hi,
                         unsigned short* __restrict__ lo) {
    const int idx = blockIdx.x * 256 + threadIdx.x;
    if (idx >= 10 * 40 * 64 * 8) return;
    const int e = idx & 7;
    const int lane = (idx >> 3) & 63;
    const int nt = (idx >> 9) % 40;
    const int kt = idx / 20480;
    const int r = lane & 15, g = lane >> 4;
    const int col = nt * 16 + r;
    const int k = kt * 32 + g * 8 + e;
    const float w = (col < EMB2 && k < EMB) ? W[(size_t)k * EMB2 + col] : 0.f;
    const unsigned short h = ftobf(w);
    hi[idx] = h;
    lo[idx] = ftobf(w - u16tof(h));
}
__global__ void k_wconv2(const float* __restrict__ W, unsigned short* __restrict__ hi,
                         unsigned short* __restrict__ lo) {
    const int idx = blockIdx.x * 256 + threadIdx.x;
    if (idx >= 19 * 20 * 64 * 8) return;
    const int e = idx & 7;
    const int lane = (idx >> 3) & 63;
    const int nt = (idx >> 9) % 20;
    const int kt = idx / 10240;
    const int r = lane & 15, g = lane >> 4;
    const int col = nt * 16 + r;
    const int k = kt * 32 + g * 8 + e;
    const float w = (col < EMB && k < EMB2) ? W[(size_t)k * EMB + col] : 0.f;
    const unsigned short h = ftobf(w);
    hi[idx] = h;
    lo[idx] = ftobf(w - u16tof(h));
}

// ---- MFMA GEMM1: 64-row blocks, 1024 thr (16 waves = 2 row-halves x 8 col-waves) ----
// Same per-wave working set as the 32-row version (occupancy-neutral); halves per-block
// L2 weight re-reads. 2-deep prefetch + weakened barrier; fused BN1 stats (16-way spread).
__global__ __launch_bounds__(1024) void k_mfma1(
    float* __restrict__ P, float* Q,
    const unsigned short* __restrict__ whi, const unsigned short* __restrict__ wlo,
    float* __restrict__ sum1p, float* __restrict__ ss1p)
{
    __shared__ __align__(16) short AsH[3][2048];
    __shared__ __align__(16) short AsL[3][2048];
    const int tid = threadIdx.x;
    const int lane = tid & 63;
    const int wn = tid >> 6;            // 0..15
    const int wr = wn >> 3;             // row-half 0..1
    const int wc = wn & 7;              // col-wave 0..7
    const int g = lane >> 4, r = lane & 15;
    const int row0 = blockIdx.x * 64;
    const int cp = (blockIdx.x & (NCOPY - 1)) * EMB2;
    // staging: 1024 thr x float2 = 64 rows x 32 k
    const int se2 = (tid & 3) * 2, str = (tid >> 2) & 15, stg = (tid >> 6) & 3, srg = tid >> 8;
    const int srow = row0 + srg * 16 + str;
    const int sldo = tid * 2;
    f32x4 acc[2][5];
#pragma unroll
    for (int rg = 0; rg < 2; ++rg)
#pragma unroll
        for (int t = 0; t < 5; ++t) acc[rg][t] = (f32x4){0.f, 0.f, 0.f, 0.f};

    auto loadA = [&](int kt, float2& v) {
        const int cc = kt * 32 + stg * 8 + se2;
        v = (float2){0.f, 0.f};
        if (srow < NN && cc + 1 < EMB) v = *(const float2*)(Q + (size_t)srow * EMB + cc);
    };
    auto writeA = [&](int b, float2 v) {
        bf16x2 h2, l2;
        const unsigned short hx = ftobf(v.x);
        h2[0] = (short)hx; l2[0] = (short)ftobf(v.x - u16tof(hx));
        const unsigned short hy = ftobf(v.y);
        h2[1] = (short)hy; l2[1] = (short)ftobf(v.y - u16tof(hy));
        *(bf16x2*)(&AsH[b][sldo]) = h2;
        *(bf16x2*)(&AsL[b][sldo]) = l2;
    };

    {
        float2 v0;
        loadA(0, v0);
        writeA(0, v0);
    }
    float2 vpend;
    loadA(1, vpend);      // stays in flight across the weakened barrier
    BAR_LGKM();

    for (int kt = 0; kt < 10; ++kt) {
        const int cur = kt - (kt / 3) * 3;          // kt % 3
        float2 vnext = {0.f, 0.f};
        if (kt + 2 < 10) loadA(kt + 2, vnext);      // 2-deep prefetch
        bf16x8 ah[2], al[2];
#pragma unroll
        for (int rg = 0; rg < 2; ++rg) {
            const int reg = wr * 2 + rg;            // 16-row region 0..3
            ah[rg] = *(const bf16x8*)(&AsH[cur][reg * 512 + lane * 8]);
            al[rg] = *(const bf16x8*)(&AsL[cur][reg * 512 + lane * 8]);
        }
#pragma unroll
        for (int t = 0; t < 5; ++t) {
            const size_t wb = ((size_t)(kt * 40 + wc + t * 8) * 64 + lane) * 8;
            const bf16x8 bh = *(const bf16x8*)(whi + wb);
            const bf16x8 bl = *(const bf16x8*)(wlo + wb);
#pragma unroll
            for (int rg = 0; rg < 2; ++rg) {
                acc[rg][t] = mfma16(al[rg], bh, acc[rg][t]);
                acc[rg][t] = mfma16(ah[rg], bl, acc[rg][t]);
                acc[rg][t] = mfma16(ah[rg], bh, acc[rg][t]);
            }
        }
        if (kt + 1 < 10) {
            const int nb = (kt + 1) - ((kt + 1) / 3) * 3;
            writeA(nb, vpend);
        }
        vpend = vnext;
        BAR_LGKM();
    }
    // epilogue: C writes + per-column partial stats (this wave's 32-row half)
#pragma unroll
    for (int t = 0; t < 5; ++t) {
        const int col = (wc + t * 8) * 16 + r;
        float s = 0.f, q = 0.f;
#pragma unroll
        for (int rg = 0; rg < 2; ++rg) {
            const int orow = row0 + (wr * 2 + rg) * 16 + g * 4;
#pragma unroll
            for (int j = 0; j < 4; ++j) {
                const float val = acc[rg][t][j];
                s += val; q += val * val;
                if (orow + j < NN) {
                    if (col < EMB)       Q[(size_t)(orow + j) * EMB + col] = val;
                    else if (col < EMB2) P[(size_t)(orow + j) * EMB + (col - EMB)] = val;
                }
            }
        }
        s += __shfl_xor(s, 16); s += __shfl_xor(s, 32);
        q += __shfl_xor(q, 16); q += __shfl_xor(q, 32);
        if (g == 0 && col < EMB2) {
            atomicAdd(&sum1p[cp + col], s);
            atomicAdd(&ss1p[cp + col], q);
        }
    }
}

// ---- MFMA GEMM2: 64-row blocks, 512 thr (8 waves = 2 row-halves x 4 col-waves) ----
// (CONTROL, unchanged from R32.)
__global__ __launch_bounds__(512) void k_mfma2(
    float* P, const float* __restrict__ Qa,
    const float* __restrict__ sc, const float* __restrict__ sh,
    const unsigned short* __restrict__ whi, const unsigned short* __restrict__ wlo,
    float* __restrict__ sum2p, float* __restrict__ ss2p)
{
    __shared__ __align__(16) short AsH[3][2048];
    __shared__ __align__(16) short AsL[3][2048];
    const int tid = threadIdx.x;
    const int lane = tid & 63;
    const int wn = tid >> 6;            // 0..7
    const int wr = wn >> 2;             // row-half 0..1
    const int wc = wn & 3;              // col-wave 0..3
    const int g = lane >> 4, r = lane & 15;
    const int row0 = blockIdx.x * 64;
    const int cp = (blockIdx.x & (NCOPY - 1)) * EMB;
    // staging: 512 thr x float4 = 64 rows x 32 k
    const int se4 = (tid & 1) * 4, str = (tid >> 1) & 15, stg = (tid >> 5) & 3, srg = tid >> 7;
    const int srow = row0 + srg * 16 + str;
    const int sldo = tid * 4;
    f32x4 acc[2][5];
#pragma unroll
    for (int rg = 0; rg < 2; ++rg)
#pragma unroll
        for (int t = 0; t < 5; ++t) acc[rg][t] = (f32x4){0.f, 0.f, 0.f, 0.f};

    auto loadA = [&](int kt, float4& v) {
        const int cc = kt * 32 + stg * 8 + se4;
        v = (float4){0.f, 0.f, 0.f, 0.f};
        if (srow < NN) {
            if (cc + 3 < EMB)       v = *(const float4*)(Qa + (size_t)srow * EMB + cc);
            else if (cc + 3 < EMB2) v = *(const float4*)(P + (size_t)srow * EMB + (cc - EMB));
        }
    };
    auto writeA = [&](int kt, int b, float4 v) {
        const int cc = kt * 32 + stg * 8 + se4;
        if (cc + 3 < EMB2) {
            const float4 s4 = *(const float4*)(sc + cc);
            const float4 h4 = *(const float4*)(sh + cc);
            v.x = fmaxf(fmaf(v.x, s4.x, h4.x), 0.f);
            v.y = fmaxf(fmaf(v.y, s4.y, h4.y), 0.f);
            v.z = fmaxf(fmaf(v.z, s4.z, h4.z), 0.f);
            v.w = fmaxf(fmaf(v.w, s4.w, h4.w), 0.f);
        } else {
            v = (float4){0.f, 0.f, 0.f, 0.f};
        }
        bf16x4 h4v, l4v;
        const float vv[4] = {v.x, v.y, v.z, v.w};
#pragma unroll
        for (int e = 0; e < 4; ++e) {
            const unsigned short hh = ftobf(vv[e]);
            h4v[e] = (short)hh;
            l4v[e] = (short)ftobf(vv[e] - u16tof(hh));
        }
        *(bf16x4*)(&AsH[b][sldo]) = h4v;
        *(bf16x4*)(&AsL[b][sldo]) = l4v;
    };

    {
        float4 v0;
        loadA(0, v0);
        writeA(0, 0, v0);
    }
    float4 vpend;
    loadA(1, vpend);
    BAR_LGKM();

    for (int kt = 0; kt < 19; ++kt) {
        const int cur = kt - (kt / 3) * 3;
        float4 vnext = {0.f, 0.f, 0.f, 0.f};
        if (kt + 2 < 19) loadA(kt + 2, vnext);
        bf16x8 ah[2], al[2];
#pragma unroll
        for (int rg = 0; rg < 2; ++rg) {
            const int reg = wr * 2 + rg;   // 16-row region 0..3
            ah[rg] = *(const bf16x8*)(&AsH[cur][reg * 512 + lane * 8]);
            al[rg] = *(const bf16x8*)(&AsL[cur][reg * 512 + lane * 8]);
        }
#pragma unroll
        for (int t = 0; t < 5; ++t) {
            const size_t wb = ((size_t)(kt * 20 + wc + t * 4) * 64 + lane) * 8;
            const bf16x8 bh = *(const bf16x8*)(whi + wb);
            const bf16x8 bl = *(const bf16x8*)(wlo + wb);
#pragma unroll
            for (int rg = 0; rg < 2; ++rg) {
                acc[rg][t] = mfma16(al[rg], bh, acc[rg][t]);
                acc[rg][t] = mfma16(ah[rg], bl, acc[rg][t]);
                acc[rg][t] = mfma16(ah[rg], bh, acc[rg][t]);
            }
        }
        if (kt + 1 < 19) {
            const int nb = (kt + 1) - ((kt + 1) / 3) * 3;
            writeA(kt + 1, nb, vpend);
        }
        vpend = vnext;
        BAR_LGKM();
    }
    // epilogue: C writes + per-column partial stats (this wave's 32-row half)
#pragma unroll
    for (int t = 0; t < 5; ++t) {
        const int col = (wc + t * 4) * 16 + r;
        float s = 0.f, q = 0.f;
#pragma unroll
        for (int rg = 0; rg < 2; ++rg) {
            const int orow = row0 + (wr * 2 + rg) * 16 + g * 4;
#pragma unroll
            for (int j = 0; j < 4; ++j) {
                const float val = acc[rg][t][j];
                s += val; q += val * val;
                if (col < EMB && orow + j < NN)
                    P[(size_t)(orow + j) * EMB + col] = val;
            }
        }
        s += __shfl_xor(s, 16); s += __shfl_xor(s, 32);
        q += __shfl_xor(q, 16); q += __shfl_xor(q, 32);
        if (g == 0 && col < EMB) {
            atomicAdd(&sum2p[cp + col], s);
            atomicAdd(&ss2p[cp + col], q);
        }
    }
}

// ---- reduce NCOPY partial copies + compute BN scale/shift ----
__global__ void k_scale16(const float* __restrict__ psum, const float* __restrict__ pss,
                          const float* __restrict__ g, const float* __restrict__ b,
                          float* __restrict__ scale, float* __restrict__ shift, int C) {
    const int c = blockIdx.x * 256 + threadIdx.x;
    if (c >= C) return;
    float s = 0.f, q = 0.f;
#pragma unroll
    for (int k = 0; k < NCOPY; ++k) {
        s += psum[k * C + c];
        q += pss[k * C + c];
    }
    const float invN = 1.0f / (float)NN;
    const float mean = s * invN;
    const float var = q * invN - mean * mean;
    const float sc = g[c] * rsqrtf(var + BN_EPS);
    scale[c] = sc;
    shift[c] = b[c] - mean * sc;
}

__global__ void k_poolg(const void* __restrict__ batch, const float* __restrict__ h,
                        float* __restrict__ out, const int* __restrict__ flag,
                        const float* __restrict__ sc, const float* __restrict__ sh) {
    __shared__ float red[4][EMB];
    const int g = blockIdx.x;
    const int f64 = *flag;
    int lo = 0, hi = NN;
    while (lo < hi) { int mid = (lo + hi) >> 1; if (geti(batch, f64, mid) < g) lo = mid + 1; else hi = mid; }
    const int s = lo;
    hi = NN;
    while (lo < hi) { int mid = (lo + hi) >> 1; if (geti(batch, f64, mid) < g + 1) lo = mid + 1; else hi = mid; }
    const int e = lo;
    const int tx = threadIdx.x, ty = threadIdx.y;
    if (tx < 75) {
        const int c = tx * 4;
        const float4 s4 = *(const float4*)(sc + c);
        const float4 h4 = *(const float4*)(sh + c);
        float4 acc; acc.x = acc.y = acc.z = acc.w = 0.f;
        int cntr = 0;
        for (int r = s + ty; r < e; r += 4) {
            const float4 v = *(const float4*)(h + (size_t)r * EMB + c);
            acc.x += v.x; acc.y += v.y; acc.z += v.z; acc.w += v.w;
            cntr++;
        }
        acc.x = fmaf(acc.x, s4.x, cntr * h4.x);
        acc.y = fmaf(acc.y, s4.y, cntr * h4.y);
        acc.z = fmaf(acc.z, s4.z, cntr * h4.z);
        acc.w = fmaf(acc.w, s4.w, cntr * h4.w);
        *(float4*)(&red[ty][c]) = acc;
    }
    __syncthreads();
    if (ty == 0 && tx < 75) {
        const int c = tx * 4;
        float4 o;
        o.x = red[0][c + 0] + red[1][c + 0] + red[2][c + 0] + red[3][c + 0];
        o.y = red[0][c + 1] + red[1][c + 1] + red[2][c + 1] + red[3][c + 1];
        o.z = red[0][c + 2] + red[1][c + 2] + red[2][c + 2] + red[3][c + 2];
        o.w = red[0][c + 3] + red[1][c + 3] + red[2][c + 3] + red[3][c + 3];
        *(float4*)(out + (size_t)g * EMB + c) = o;
    }
}

extern "C" void kernel_launch(void* const* d_in, const int* in_sizes, int n_in,
                              void* d_out, int out_size, void* d_ws, size_t ws_size,
                              hipStream_t stream) {
    const void* x     = d_in[0];
    const void* ei    = d_in[1];
    const void* eattr = d_in[2];
    const void* batch = d_in[3];
    const float* aemb = (const float*)d_in[4];
    const float* bemb = (const float*)d_in[5];
    const float* W1   = (const float*)d_in[6];
    const float* g1   = (const float*)d_in[8];
    const float* bt1  = (const float*)d_in[9];
    const float* W2   = (const float*)d_in[10];
    const float* g2   = (const float*)d_in[12];
    const float* bt2  = (const float*)d_in[13];

    char* ws = (char*)d_ws;
    const bool pre2 = (ws_size >= 2ull * BUF_BYTES + 2888640ull + 5ull * WSET);

    float* P = (float*)(ws);
    float* Q = (float*)(ws + BUF_BYTES);
    char* aux = ws + 2ull * BUF_BYTES;

    float* st = (float*)(aux);
    float* sc1  = st + 1800;  float* sh1 = st + 2400;
    float* sc2  = st + 3000;  float* sh2 = st + 3300;
    int* flag     = (int*)(aux + 16384);
    int* deg      = (int*)(aux + 16384 + 64);
    int* rowstart = (int*)(aux + 16384 + 64 + 400064);
    int* cursor   = (int*)(aux + 16384 + 64 + 800128);
    int* elist    = (int*)(aux + 16384 + 64 + 1200192);
    float* ebc    = (float*)(aux + 16384 + 64 + 2800192);
    int* bsum     = (int*)(aux + 2872192);
    int* bbase    = (int*)(aux + 2872192 + 512);
    char* wbase   = aux + 2888640;
    // BN partial copies reuse the (dead-after-setup) cursor region: 28800 floats = 115.2 KB < 400 KB
    float* parts  = (float*)cursor;
    float* sum1p  = parts;            // 16*600
    float* ss1p   = parts + 9600;     // 16*600
    float* sum2p  = parts + 19200;    // 16*300
    float* ss2p   = parts + 24000;    // 16*300

    const dim3 blk80x4(80, 4);

    k_detect<<<1, 256, 0, stream>>>((const int*)ei, flag);
    k_init<<<2, 256, 0, stream>>>(sc2, sh2);

    (void)hipMemsetAsync(deg, 0, NN * sizeof(int), stream);
    k_deg<<<(EE + 255) / 256, 256, 0, stream>>>(ei, deg, flag);
    k_scanA<<<SCAN_NB, 256, 0, stream>>>(deg, bsum);
    k_scanB<<<1, 64, 0, stream>>>(bsum, bbase, rowstart);
    k_scanC<<<SCAN_NB, 256, 0, stream>>>(deg, bbase, rowstart, cursor);
    k_scatter<<<(EE + 255) / 256, 256, 0, stream>>>(ei, eattr, cursor, elist, flag);
    k_ebc<<<60, 80, 0, stream>>>(bemb, ebc);

    if (pre2) {
        for (int i = 0; i < LL; ++i) {
            char* wb = wbase + (size_t)i * WSET;
            k_wconv1<<<(204800 + 255) / 256, 256, 0, stream>>>(
                W1 + (size_t)i * EMB * EMB2,
                (unsigned short*)wb, (unsigned short*)(wb + 409600));
            k_wconv2<<<(194560 + 255) / 256, 256, 0, stream>>>(
                W2 + (size_t)i * EMB2 * EMB,
                (unsigned short*)(wb + 819200), (unsigned short*)(wb + 819200 + 389120));
        }
    }

    k_encode<<<NN / 4, blk80x4, 0, stream>>>(x, aemb, P, flag);

    for (int i = 0; i < LL; ++i) {
        char* wb = wbase + (pre2 ? (size_t)i * WSET : 0ull);
        unsigned short* wt1hi = (unsigned short*)wb;
        unsigned short* wt1lo = (unsigned short*)(wb + 409600);
        unsigned short* wt2hi = (unsigned short*)(wb + 819200);
        unsigned short* wt2lo = (unsigned short*)(wb + 819200 + 389120);

        if (!pre2) {
            k_wconv1<<<(204800 + 255) / 256, 256, 0, stream>>>(
                W1 + (size_t)i * EMB * EMB2, wt1hi, wt1lo);
            k_wconv2<<<(194560 + 255) / 256, 256, 0, stream>>>(
                W2 + (size_t)i * EMB2 * EMB, wt2hi, wt2lo);
        }
        (void)hipMemsetAsync(parts, 0, 28800 * sizeof(float), stream);

        k_gather<<<NN / 4, blk80x4, 0, stream>>>(rowstart, elist, ebc, P, Q,
                                                 sc2, sh2, (i > 0) ? 1 : 0);

        // z1 = z @ W1 (+ fused BN1 partial stats): z1a -> Q in-place, z1b -> P
        k_mfma1<<<(NN + 63) / 64, 1024, 0, stream>>>(P, Q, wt1hi, wt1lo, sum1p, ss1p);
        k_scale16<<<3, 256, 0, stream>>>(sum1p, ss1p, g1 + (size_t)i * EMB2,
                                         bt1 + (size_t)i * EMB2, sc1, sh1, EMB2);

        // h_pre = relu(BN1([Q|P])) @ W2 -> P in-place (+ fused BN2 partial stats)
        k_mfma2<<<(NN + 63) / 64, 512, 0, stream>>>(P, Q, sc1, sh1, wt2hi, wt2lo, sum2p, ss2p);
        k_scale16<<<2, 256, 0, stream>>>(sum2p, ss2p, g2 + (size_t)i * EMB,
                                         bt2 + (size_t)i * EMB, sc2, sh2, EMB);
    }

    k_poolg<<<GG, blk80x4, 0, stream>>>(batch, P, (float*)d_out, flag, sc2, sh2);
}

// Round 34
// 2602.682 us; speedup vs baseline: 1.0944x; 1.0944x over previous
//
#include <hip/hip_runtime.h>

#define NN 100000
#define EE 400000
#define GG 4000
#define EMB 300
#define EMB2 600
#define LL 5
#define BN_EPS 1e-5f
#define BUF_BYTES 120000000ull
#define SCAN_NB 98
#define WSET 1597440ull
#define NCOPY 16

// barrier with LDS-only drain: leaves global prefetch loads in flight (T4)
#define BAR_LGKM() asm volatile("s_waitcnt lgkmcnt(0)\ns_barrier" ::: "memory")

typedef __attribute__((ext_vector_type(8))) short bf16x8;
typedef __attribute__((ext_vector_type(4))) short bf16x4;
typedef __attribute__((ext_vector_type(2))) short bf16x2;
typedef __attribute__((ext_vector_type(4))) float f32x4;

__device__ __constant__ int c_atom_off[9] = {0,119,123,135,147,157,163,169,171};

static __device__ __forceinline__ float u16tof(unsigned short u) {
    return __uint_as_float(((unsigned int)u) << 16);
}
static __device__ __forceinline__ unsigned short ftobf(float f) {
    unsigned int u = __float_as_uint(f);
    unsigned int r = 0x7fffu + ((u >> 16) & 1u);
    return (unsigned short)((u + r) >> 16);
}
static __device__ __forceinline__ int geti(const void* p, int f64, long long i) {
    return f64 ? (int)((const long long*)p)[i] : ((const int*)p)[i];
}
static __device__ __forceinline__ f32x4 mfma16(bf16x8 a, bf16x8 b, f32x4 c) {
    return __builtin_amdgcn_mfma_f32_16x16x32_bf16(a, b, c, 0, 0, 0);
}

__global__ void k_detect(const int* __restrict__ ei, int* __restrict__ flag) {
    __shared__ int cnt;
    if (threadIdx.x == 0) cnt = 0;
    __syncthreads();
    int z = 0;
    for (int i = threadIdx.x; i < 1024; i += 256)
        if (ei[2 * i + 1] == 0) z++;
    atomicAdd(&cnt, z);
    __syncthreads();
    if (threadIdx.x == 0) *flag = (cnt > 512) ? 1 : 0;
}

__global__ void k_init(float* __restrict__ sc2, float* __restrict__ sh2) {
    const int c = blockIdx.x * 256 + threadIdx.x;
    if (c < EMB) { sc2[c] = 1.f; sh2[c] = 0.f; }
}

__global__ void k_encode(const void* __restrict__ x, const float* __restrict__ aemb,
                         float* __restrict__ h, const int* __restrict__ flag) {
    __shared__ int xi[4][9];
    const int ty = threadIdx.y, tx = threadIdx.x;
    const int n = blockIdx.x * 4 + ty;
    const int f64 = *flag;
    if (tx < 9) xi[ty][tx] = geti(x, f64, (long long)n * 9 + tx) + c_atom_off[tx];
    __syncthreads();
    if (tx < 75) {
        const int c = tx * 4;
        float s0 = 0.f, s1 = 0.f, s2 = 0.f, s3 = 0.f;
#pragma unroll
        for (int f = 0; f < 9; ++f) {
            const float4 v = *(const float4*)(aemb + (size_t)xi[ty][f] * EMB + c);
            s0 += v.x; s1 += v.y; s2 += v.z; s3 += v.w;
        }
        float4 o; o.x = s0; o.y = s1; o.z = s2; o.w = s3;
        *(float4*)(h + (size_t)n * EMB + c) = o;
    }
}

__global__ void k_deg(const void* __restrict__ ei, int* __restrict__ deg,
                      const int* __restrict__ flag) {
    const int e = blockIdx.x * 256 + threadIdx.x;
    if (e < EE) atomicAdd(&deg[geti(ei, *flag, (long long)EE + e)], 1);
}

__global__ void k_scanA(const int* __restrict__ deg, int* __restrict__ bsum) {
    __shared__ int red[256];
    const int b = blockIdx.x, t = threadIdx.x;
    const int base = b * 1024 + t * 4;
    int s = 0;
#pragma unroll
    for (int e = 0; e < 4; ++e) {
        const int i = base + e;
        if (i < NN) s += deg[i];
    }
    red[t] = s;
    __syncthreads();
    for (int off = 128; off > 0; off >>= 1) {
        if (t < off) red[t] += red[t + off];
        __syncthreads();
    }
    if (t == 0) bsum[b] = red[0];
}

__global__ void k_scanB(const int* __restrict__ bsum, int* __restrict__ bbase,
                        int* __restrict__ rowstart) {
    if (threadIdx.x == 0) {
        int run = 0;
        for (int b = 0; b < SCAN_NB; ++b) { bbase[b] = run; run += bsum[b]; }
        rowstart[NN] = run;
    }
}

__global__ void k_scanC(const int* __restrict__ deg, const int* __restrict__ bbase,
                        int* __restrict__ rowstart, int* __restrict__ cursor) {
    __shared__ int ts[256];
    const int b = blockIdx.x, t = threadIdx.x;
    const int base = b * 1024 + t * 4;
    int loc[4];
    int s = 0;
#pragma unroll
    for (int e = 0; e < 4; ++e) {
        const int i = base + e;
        loc[e] = (i < NN) ? deg[i] : 0;
        s += loc[e];
    }
    ts[t] = s;
    __syncthreads();
    for (int off = 1; off < 256; off <<= 1) {
        const int v = (t >= off) ? ts[t - off] : 0;
        __syncthreads();
        ts[t] += v;
        __syncthreads();
    }
    int run = bbase[b] + ts[t] - s;
#pragma unroll
    for (int e = 0; e < 4; ++e) {
        const int i = base + e;
        if (i < NN) { rowstart[i] = run; cursor[i] = run; run += loc[e]; }
    }
}

__global__ void k_scatter(const void* __restrict__ ei, const void* __restrict__ eattr,
                          int* __restrict__ cursor, int* __restrict__ elist,
                          const int* __restrict__ flag) {
    const int e = blockIdx.x * 256 + threadIdx.x;
    if (e >= EE) return;
    const int f64 = *flag;
    const int src = geti(ei, f64, e);
    const int dst = geti(ei, f64, (long long)EE + e);
    const int b0 = geti(eattr, f64, (long long)e * 3 + 0);
    const int b1 = geti(eattr, f64, (long long)e * 3 + 1);
    const int b2 = geti(eattr, f64, (long long)e * 3 + 2);
    const int pos = atomicAdd(&cursor[dst], 1);
    elist[pos] = src * 64 + b0 * 12 + b1 * 2 + b2;
}

__global__ void k_ebc(const float* __restrict__ bemb, float* __restrict__ ebc) {
    const int cb = blockIdx.x;
    const int tx = threadIdx.x;
    if (tx >= 75) return;
    const int b0 = cb / 12, b1 = (cb / 2) % 6, b2 = cb & 1;
    const int c = tx * 4;
    const float4 v0 = *(const float4*)(bemb + (size_t)b0 * EMB + c);
    const float4 v1 = *(const float4*)(bemb + (size_t)(5 + b1) * EMB + c);
    const float4 v2 = *(const float4*)(bemb + (size_t)(11 + b2) * EMB + c);
    float4 o; o.x = v0.x + v1.x + v2.x; o.y = v0.y + v1.y + v2.y;
    o.z = v0.z + v1.z + v2.z; o.w = v0.w + v1.w + v2.w;
    *(float4*)(ebc + (size_t)cb * EMB + c) = o;
}

// ---- gather: 4 nodes/block, batched edge loads, fused BN2+relu ----
__global__ void k_gather(const int* __restrict__ rowstart, const int* __restrict__ elist,
                         const float* __restrict__ ebc,
                         const float* __restrict__ h, float* __restrict__ z,
                         const float* __restrict__ sc, const float* __restrict__ sh,
                         int dorelu) {
    const int ty = threadIdx.y, tx = threadIdx.x;
    const int n = blockIdx.x * 4 + ty;
    if (tx >= 75) return;
    const int c = tx * 4;
    const float4 s4 = *(const float4*)(sc + c);
    const float4 h4 = *(const float4*)(sh + c);
    const int s = rowstart[n], e = rowstart[n + 1];
    float4 acc;
    {
        float4 v = *(const float4*)(h + (size_t)n * EMB + c);
        v.x = fmaf(v.x, s4.x, h4.x); v.y = fmaf(v.y, s4.y, h4.y);
        v.z = fmaf(v.z, s4.z, h4.z); v.w = fmaf(v.w, s4.w, h4.w);
        if (dorelu) {
            v.x = fmaxf(v.x, 0.f); v.y = fmaxf(v.y, 0.f);
            v.z = fmaxf(v.z, 0.f); v.w = fmaxf(v.w, 0.f);
        }
        acc = v;
    }
    for (int j = s; j < e; j += 4) {
        const int m = e - j;
        int pk[4];
#pragma unroll
        for (int d = 0; d < 4; ++d) pk[d] = (d < m) ? elist[j + d] : 0;
        float4 hv[4], ev[4];
#pragma unroll
        for (int d = 0; d < 4; ++d) {
            if (d < m) {
                const int src = pk[d] >> 6, cb = pk[d] & 63;
                hv[d] = *(const float4*)(h + (size_t)src * EMB + c);
                ev[d] = *(const float4*)(ebc + (size_t)cb * EMB + c);
            }
        }
#pragma unroll
        for (int d = 0; d < 4; ++d) {
            if (d < m) {
                float4 t = hv[d];
                t.x = fmaf(t.x, s4.x, h4.x); t.y = fmaf(t.y, s4.y, h4.y);
                t.z = fmaf(t.z, s4.z, h4.z); t.w = fmaf(t.w, s4.w, h4.w);
                if (dorelu) {
                    t.x = fmaxf(t.x, 0.f); t.y = fmaxf(t.y, 0.f);
                    t.z = fmaxf(t.z, 0.f); t.w = fmaxf(t.w, 0.f);
                }
                acc.x += fmaxf(t.x + ev[d].x, 0.f);
                acc.y += fmaxf(t.y + ev[d].y, 0.f);
                acc.z += fmaxf(t.z + ev[d].z, 0.f);
                acc.w += fmaxf(t.w + ev[d].w, 0.f);
            }
        }
    }
    *(float4*)(z + (size_t)n * EMB + c) = acc;
}

__global__ void k_wconv1(const float* __restrict__ W, unsigned short* __restrict__ hi,
                         unsigned short* __restrict__ lo) {
    const int idx = blockIdx.x * 256 + threadIdx.x;
    if (idx >= 10 * 40 * 64 * 8) return;
    const int e = idx & 7;
    const int lane = (idx >> 3) & 63;
    const int nt = (idx >> 9) % 40;
    const int kt = idx / 20480;
    const int r = lane & 15, g = lane >> 4;
    const int col = nt * 16 + r;
    const int k = kt * 32 + g * 8 + e;
    const float w = (col < EMB2 && k < EMB) ? W[(size_t)k * EMB2 + col] : 0.f;
    const unsigned short h = ftobf(w);
    hi[idx] = h;
    lo[idx] = ftobf(w - u16tof(h));
}
__global__ void k_wconv2(const float* __restrict__ W, unsigned short* __restrict__ hi,
                         unsigned short* __restrict__ lo) {
    const int idx = blockIdx.x * 256 + threadIdx.x;
    if (idx >= 19 * 20 * 64 * 8) return;
    const int e = idx & 7;
    const int lane = (idx >> 3) & 63;
    const int nt = (idx >> 9) % 20;
    const int kt = idx / 10240;
    const int r = lane & 15, g = lane >> 4;
    const int col = nt * 16 + r;
    const int k = kt * 32 + g * 8 + e;
    const float w = (col < EMB && k < EMB2) ? W[(size_t)k * EMB + col] : 0.f;
    const unsigned short h = ftobf(w);
    hi[idx] = h;
    lo[idx] = ftobf(w - u16tof(h));
}

// ---- MFMA GEMM1: 32-row blocks, 512 thr; 2-deep prefetch + weakened barrier ----
// z1a (cols<300) -> Q in-place, z1b (300-599) -> P. Fused BN1 partial stats (16-way spread).
__global__ __launch_bounds__(512) void k_mfma1(
    float* __restrict__ P, float* Q,
    const unsigned short* __restrict__ whi, const unsigned short* __restrict__ wlo,
    float* __restrict__ sum1p, float* __restrict__ ss1p)
{
    __shared__ __align__(16) short AsH[3][1024];
    __shared__ __align__(16) short AsL[3][1024];
    const int tid = threadIdx.x;
    const int lane = tid & 63;
    const int wn = tid >> 6;
    const int g = lane >> 4, r = lane & 15;
    const int row0 = blockIdx.x * 32;
    const int cp = (blockIdx.x & (NCOPY - 1)) * EMB2;
    const int se2 = (tid & 3) * 2, str = (tid >> 2) & 15, stg = (tid >> 6) & 3, srg = tid >> 8;
    const int srow = row0 + srg * 16 + str;
    const int sldo = tid * 2;
    f32x4 acc[2][5];
#pragma unroll
    for (int rg = 0; rg < 2; ++rg)
#pragma unroll
        for (int t = 0; t < 5; ++t) acc[rg][t] = (f32x4){0.f, 0.f, 0.f, 0.f};

    auto loadA = [&](int kt, float2& v) {
        const int cc = kt * 32 + stg * 8 + se2;
        v = (float2){0.f, 0.f};
        if (cc + 1 < EMB) v = *(const float2*)(Q + (size_t)srow * EMB + cc);
    };
    auto writeA = [&](int b, float2 v) {
        bf16x2 h2, l2;
        const unsigned short hx = ftobf(v.x);
        h2[0] = (short)hx; l2[0] = (short)ftobf(v.x - u16tof(hx));
        const unsigned short hy = ftobf(v.y);
        h2[1] = (short)hy; l2[1] = (short)ftobf(v.y - u16tof(hy));
        *(bf16x2*)(&AsH[b][sldo]) = h2;
        *(bf16x2*)(&AsL[b][sldo]) = l2;
    };

    {
        float2 v0;
        loadA(0, v0);
        writeA(0, v0);
    }
    float2 vpend;
    loadA(1, vpend);      // stays in flight across the weakened barrier
    BAR_LGKM();

    for (int kt = 0; kt < 10; ++kt) {
        const int cur = kt - (kt / 3) * 3;          // kt % 3
        float2 vnext = {0.f, 0.f};
        if (kt + 2 < 10) loadA(kt + 2, vnext);      // 2-deep prefetch
        bf16x8 ah[2], al[2];
#pragma unroll
        for (int rg = 0; rg < 2; ++rg) {
            ah[rg] = *(const bf16x8*)(&AsH[cur][rg * 512 + lane * 8]);
            al[rg] = *(const bf16x8*)(&AsL[cur][rg * 512 + lane * 8]);
        }
#pragma unroll
        for (int t = 0; t < 5; ++t) {
            const size_t wb = ((size_t)(kt * 40 + wn + t * 8) * 64 + lane) * 8;
            const bf16x8 bh = *(const bf16x8*)(whi + wb);
            const bf16x8 bl = *(const bf16x8*)(wlo + wb);
#pragma unroll
            for (int rg = 0; rg < 2; ++rg) {
                acc[rg][t] = mfma16(al[rg], bh, acc[rg][t]);
                acc[rg][t] = mfma16(ah[rg], bl, acc[rg][t]);
                acc[rg][t] = mfma16(ah[rg], bh, acc[rg][t]);
            }
        }
        if (kt + 1 < 10) {
            const int nb = (kt + 1) - ((kt + 1) / 3) * 3;
            writeA(nb, vpend);
        }
        vpend = vnext;
        BAR_LGKM();
    }
    // epilogue: C writes + per-column partial stats (32 rows of this block)
#pragma unroll
    for (int t = 0; t < 5; ++t) {
        const int col = (wn + t * 8) * 16 + r;
        float s = 0.f, q = 0.f;
#pragma unroll
        for (int rg = 0; rg < 2; ++rg) {
            const int orow = row0 + rg * 16 + g * 4;
#pragma unroll
            for (int j = 0; j < 4; ++j) {
                const float val = acc[rg][t][j];
                s += val; q += val * val;
                if (col < EMB)       Q[(size_t)(orow + j) * EMB + col] = val;
                else if (col < EMB2) P[(size_t)(orow + j) * EMB + (col - EMB)] = val;
            }
        }
        s += __shfl_xor(s, 16); s += __shfl_xor(s, 32);
        q += __shfl_xor(q, 16); q += __shfl_xor(q, 32);
        if (g == 0 && col < EMB2) {
            atomicAdd(&sum1p[cp + col], s);
            atomicAdd(&ss1p[cp + col], q);
        }
    }
}

// ---- MFMA GEMM2: 64-row blocks, 512 thr (8 waves = 2 row-halves x 4 col-waves) ----
// Halves per-block weight re-reads from L2 and doubles per-block wave parallelism.
// 2-deep prefetch + weakened barrier; fused BN2 partial stats (16-way spread).
__global__ __launch_bounds__(512) void k_mfma2(
    float* P, const float* __restrict__ Qa,
    const float* __restrict__ sc, const float* __restrict__ sh,
    const unsigned short* __restrict__ whi, const unsigned short* __restrict__ wlo,
    float* __restrict__ sum2p, float* __restrict__ ss2p)
{
    __shared__ __align__(16) short AsH[3][2048];
    __shared__ __align__(16) short AsL[3][2048];
    const int tid = threadIdx.x;
    const int lane = tid & 63;
    const int wn = tid >> 6;            // 0..7
    const int wr = wn >> 2;             // row-half 0..1
    const int wc = wn & 3;              // col-wave 0..3
    const int g = lane >> 4, r = lane & 15;
    const int row0 = blockIdx.x * 64;
    const int cp = (blockIdx.x & (NCOPY - 1)) * EMB;
    // staging: 512 thr x float4 = 64 rows x 32 k
    const int se4 = (tid & 1) * 4, str = (tid >> 1) & 15, stg = (tid >> 5) & 3, srg = tid >> 7;
    const int srow = row0 + srg * 16 + str;
    const int sldo = tid * 4;
    f32x4 acc[2][5];
#pragma unroll
    for (int rg = 0; rg < 2; ++rg)
#pragma unroll
        for (int t = 0; t < 5; ++t) acc[rg][t] = (f32x4){0.f, 0.f, 0.f, 0.f};

    auto loadA = [&](int kt, float4& v) {
        const int cc = kt * 32 + stg * 8 + se4;
        v = (float4){0.f, 0.f, 0.f, 0.f};
        if (srow < NN) {
            if (cc + 3 < EMB)       v = *(const float4*)(Qa + (size_t)srow * EMB + cc);
            else if (cc + 3 < EMB2) v = *(const float4*)(P + (size_t)srow * EMB + (cc - EMB));
        }
    };
    auto writeA = [&](int kt, int b, float4 v) {
        const int cc = kt * 32 + stg * 8 + se4;
        if (cc + 3 < EMB2) {
            const float4 s4 = *(const float4*)(sc + cc);
            const float4 h4 = *(const float4*)(sh + cc);
            v.x = fmaxf(fmaf(v.x, s4.x, h4.x), 0.f);
            v.y = fmaxf(fmaf(v.y, s4.y, h4.y), 0.f);
            v.z = fmaxf(fmaf(v.z, s4.z, h4.z), 0.f);
            v.w = fmaxf(fmaf(v.w, s4.w, h4.w), 0.f);
        } else {
            v = (float4){0.f, 0.f, 0.f, 0.f};
        }
        bf16x4 h4v, l4v;
        const float vv[4] = {v.x, v.y, v.z, v.w};
#pragma unroll
        for (int e = 0; e < 4; ++e) {
            const unsigned short hh = ftobf(vv[e]);
            h4v[e] = (short)hh;
            l4v[e] = (short)ftobf(vv[e] - u16tof(hh));
        }
        *(bf16x4*)(&AsH[b][sldo]) = h4v;
        *(bf16x4*)(&AsL[b][sldo]) = l4v;
    };

    {
        float4 v0;
        loadA(0, v0);
        writeA(0, 0, v0);
    }
    float4 vpend;
    loadA(1, vpend);
    BAR_LGKM();

    for (int kt = 0; kt < 19; ++kt) {
        const int cur = kt - (kt / 3) * 3;
        float4 vnext = {0.f, 0.f, 0.f, 0.f};
        if (kt + 2 < 19) loadA(kt + 2, vnext);
        bf16x8 ah[2], al[2];
#pragma unroll
        for (int rg = 0; rg < 2; ++rg) {
            const int reg = wr * 2 + rg;   // 16-row region 0..3
            ah[rg] = *(const bf16x8*)(&AsH[cur][reg * 512 + lane * 8]);
            al[rg] = *(const bf16x8*)(&AsL[cur][reg * 512 + lane * 8]);
        }
#pragma unroll
        for (int t = 0; t < 5; ++t) {
            const size_t wb = ((size_t)(kt * 20 + wc + t * 4) * 64 + lane) * 8;
            const bf16x8 bh = *(const bf16x8*)(whi + wb);
            const bf16x8 bl = *(const bf16x8*)(wlo + wb);
#pragma unroll
            for (int rg = 0; rg < 2; ++rg) {
                acc[rg][t] = mfma16(al[rg], bh, acc[rg][t]);
                acc[rg][t] = mfma16(ah[rg], bl, acc[rg][t]);
                acc[rg][t] = mfma16(ah[rg], bh, acc[rg][t]);
            }
        }
        if (kt + 1 < 19) {
            const int nb = (kt + 1) - ((kt + 1) / 3) * 3;
            writeA(kt + 1, nb, vpend);
        }
        vpend = vnext;
        BAR_LGKM();
    }
    // epilogue: C writes + per-column partial stats (this wave's 32-row half)
#pragma unroll
    for (int t = 0; t < 5; ++t) {
        const int col = (wc + t * 4) * 16 + r;
        float s = 0.f, q = 0.f;
#pragma unroll
        for (int rg = 0; rg < 2; ++rg) {
            const int orow = row0 + (wr * 2 + rg) * 16 + g * 4;
#pragma unroll
            for (int j = 0; j < 4; ++j) {
                const float val = acc[rg][t][j];
                s += val; q += val * val;
                if (col < EMB && orow + j < NN)
                    P[(size_t)(orow + j) * EMB + col] = val;
            }
        }
        s += __shfl_xor(s, 16); s += __shfl_xor(s, 32);
        q += __shfl_xor(q, 16); q += __shfl_xor(q, 32);
        if (g == 0 && col < EMB) {
            atomicAdd(&sum2p[cp + col], s);
            atomicAdd(&ss2p[cp + col], q);
        }
    }
}

// ---- reduce NCOPY partial copies + compute BN scale/shift ----
__global__ void k_scale16(const float* __restrict__ psum, const float* __restrict__ pss,
                          const float* __restrict__ g, const float* __restrict__ b,
                          float* __restrict__ scale, float* __restrict__ shift, int C) {
    const int c = blockIdx.x * 256 + threadIdx.x;
    if (c >= C) return;
    float s = 0.f, q = 0.f;
#pragma unroll
    for (int k = 0; k < NCOPY; ++k) {
        s += psum[k * C + c];
        q += pss[k * C + c];
    }
    const float invN = 1.0f / (float)NN;
    const float mean = s * invN;
    const float var = q * invN - mean * mean;
    const float sc = g[c] * rsqrtf(var + BN_EPS);
    scale[c] = sc;
    shift[c] = b[c] - mean * sc;
}

__global__ void k_poolg(const void* __restrict__ batch, const float* __restrict__ h,
                        float* __restrict__ out, const int* __restrict__ flag,
                        const float* __restrict__ sc, const float* __restrict__ sh) {
    __shared__ float red[4][EMB];
    const int g = blockIdx.x;
    const int f64 = *flag;
    int lo = 0, hi = NN;
    while (lo < hi) { int mid = (lo + hi) >> 1; if (geti(batch, f64, mid) < g) lo = mid + 1; else hi = mid; }
    const int s = lo;
    hi = NN;
    while (lo < hi) { int mid = (lo + hi) >> 1; if (geti(batch, f64, mid) < g + 1) lo = mid + 1; else hi = mid; }
    const int e = lo;
    const int tx = threadIdx.x, ty = threadIdx.y;
    if (tx < 75) {
        const int c = tx * 4;
        const float4 s4 = *(const float4*)(sc + c);
        const float4 h4 = *(const float4*)(sh + c);
        float4 acc; acc.x = acc.y = acc.z = acc.w = 0.f;
        int cntr = 0;
        for (int r = s + ty; r < e; r += 4) {
            const float4 v = *(const float4*)(h + (size_t)r * EMB + c);
            acc.x += v.x; acc.y += v.y; acc.z += v.z; acc.w += v.w;
            cntr++;
        }
        acc.x = fmaf(acc.x, s4.x, cntr * h4.x);
        acc.y = fmaf(acc.y, s4.y, cntr * h4.y);
        acc.z = fmaf(acc.z, s4.z, cntr * h4.z);
        acc.w = fmaf(acc.w, s4.w, cntr * h4.w);
        *(float4*)(&red[ty][c]) = acc;
    }
    __syncthreads();
    if (ty == 0 && tx < 75) {
        const int c = tx * 4;
        float4 o;
        o.x = red[0][c + 0] + red[1][c + 0] + red[2][c + 0] + red[3][c + 0];
        o.y = red[0][c + 1] + red[1][c + 1] + red[2][c + 1] + red[3][c + 1];
        o.z = red[0][c + 2] + red[1][c + 2] + red[2][c + 2] + red[3][c + 2];
        o.w = red[0][c + 3] + red[1][c + 3] + red[2][c + 3] + red[3][c + 3];
        *(float4*)(out + (size_t)g * EMB + c) = o;
    }
}

extern "C" void kernel_launch(void* const* d_in, const int* in_sizes, int n_in,
                              void* d_out, int out_size, void* d_ws, size_t ws_size,
                              hipStream_t stream) {
    const void* x     = d_in[0];
    const void* ei    = d_in[1];
    const void* eattr = d_in[2];
    const void* batch = d_in[3];
    const float* aemb = (const float*)d_in[4];
    const float* bemb = (const float*)d_in[5];
    const float* W1   = (const float*)d_in[6];
    const float* g1   = (const float*)d_in[8];
    const float* bt1  = (const float*)d_in[9];
    const float* W2   = (const float*)d_in[10];
    const float* g2   = (const float*)d_in[12];
    const float* bt2  = (const float*)d_in[13];

    char* ws = (char*)d_ws;
    const bool pre2 = (ws_size >= 2ull * BUF_BYTES + 2888640ull + 5ull * WSET);

    float* P = (float*)(ws);
    float* Q = (float*)(ws + BUF_BYTES);
    char* aux = ws + 2ull * BUF_BYTES;

    float* st = (float*)(aux);
    float* sc1  = st + 1800;  float* sh1 = st + 2400;
    float* sc2  = st + 3000;  float* sh2 = st + 3300;
    int* flag     = (int*)(aux + 16384);
    int* deg      = (int*)(aux + 16384 + 64);
    int* rowstart = (int*)(aux + 16384 + 64 + 400064);
    int* cursor   = (int*)(aux + 16384 + 64 + 800128);
    int* elist    = (int*)(aux + 16384 + 64 + 1200192);
    float* ebc    = (float*)(aux + 16384 + 64 + 2800192);
    int* bsum     = (int*)(aux + 2872192);
    int* bbase    = (int*)(aux + 2872192 + 512);
    char* wbase   = aux + 2888640;
    // BN partial copies reuse the (dead-after-setup) cursor region: 28800 floats = 115.2 KB < 400 KB
    float* parts  = (float*)cursor;
    float* sum1p  = parts;            // 16*600
    float* ss1p   = parts + 9600;     // 16*600
    float* sum2p  = parts + 19200;    // 16*300
    float* ss2p   = parts + 24000;    // 16*300

    const dim3 blk80x4(80, 4);

    k_detect<<<1, 256, 0, stream>>>((const int*)ei, flag);
    k_init<<<2, 256, 0, stream>>>(sc2, sh2);

    (void)hipMemsetAsync(deg, 0, NN * sizeof(int), stream);
    k_deg<<<(EE + 255) / 256, 256, 0, stream>>>(ei, deg, flag);
    k_scanA<<<SCAN_NB, 256, 0, stream>>>(deg, bsum);
    k_scanB<<<1, 64, 0, stream>>>(bsum, bbase, rowstart);
    k_scanC<<<SCAN_NB, 256, 0, stream>>>(deg, bbase, rowstart, cursor);
    k_scatter<<<(EE + 255) / 256, 256, 0, stream>>>(ei, eattr, cursor, elist, flag);
    k_ebc<<<60, 80, 0, stream>>>(bemb, ebc);

    if (pre2) {
        for (int i = 0; i < LL; ++i) {
            char* wb = wbase + (size_t)i * WSET;
            k_wconv1<<<(204800 + 255) / 256, 256, 0, stream>>>(
                W1 + (size_t)i * EMB * EMB2,
                (unsigned short*)wb, (unsigned short*)(wb + 409600));
            k_wconv2<<<(194560 + 255) / 256, 256, 0, stream>>>(
                W2 + (size_t)i * EMB2 * EMB,
                (unsigned short*)(wb + 819200), (unsigned short*)(wb + 819200 + 389120));
        }
    }

    k_encode<<<NN / 4, blk80x4, 0, stream>>>(x, aemb, P, flag);

    for (int i = 0; i < LL; ++i) {
        char* wb = wbase + (pre2 ? (size_t)i * WSET : 0ull);
        unsigned short* wt1hi = (unsigned short*)wb;
        unsigned short* wt1lo = (unsigned short*)(wb + 409600);
        unsigned short* wt2hi = (unsigned short*)(wb + 819200);
        unsigned short* wt2lo = (unsigned short*)(wb + 819200 + 389120);

        if (!pre2) {
            k_wconv1<<<(204800 + 255) / 256, 256, 0, stream>>>(
                W1 + (size_t)i * EMB * EMB2, wt1hi, wt1lo);
            k_wconv2<<<(194560 + 255) / 256, 256, 0, stream>>>(
                W2 + (size_t)i * EMB2 * EMB, wt2hi, wt2lo);
        }
        (void)hipMemsetAsync(parts, 0, 28800 * sizeof(float), stream);

        k_gather<<<NN / 4, blk80x4, 0, stream>>>(rowstart, elist, ebc, P, Q,
                                                 sc2, sh2, (i > 0) ? 1 : 0);

        // z1 = z @ W1 (+ fused BN1 partial stats): z1a -> Q in-place, z1b -> P
        k_mfma1<<<NN / 32, 512, 0, stream>>>(P, Q, wt1hi, wt1lo, sum1p, ss1p);
        k_scale16<<<3, 256, 0, stream>>>(sum1p, ss1p, g1 + (size_t)i * EMB2,
                                         bt1 + (size_t)i * EMB2, sc1, sh1, EMB2);

        // h_pre = relu(BN1([Q|P])) @ W2 -> P in-place (+ fused BN2 partial stats)
        k_mfma2<<<(NN + 63) / 64, 512, 0, stream>>>(P, Q, sc1, sh1, wt2hi, wt2lo, sum2p, ss2p);
        k_scale16<<<2, 256, 0, stream>>>(sum2p, ss2p, g2 + (size_t)i * EMB,
                                         bt2 + (size_t)i * EMB, sc2, sh2, EMB);
    }

    k_poolg<<<GG, blk80x4, 0, stream>>>(batch, P, (float*)d_out, flag, sc2, sh2);
}

// Round 35
// 2573.290 us; speedup vs baseline: 1.1069x; 1.0114x over previous
//
#include <hip/hip_runtime.h>

#define NN 100000
#define EE 400000
#define GG 4000
#define EMB 300
#define EMB2 600
#define LL 5
#define BN_EPS 1e-5f
#define BUF_BYTES 120000000ull
#define SCAN_NB 98
#define WSET 1597440ull
#define NCOPY 16

// barrier with LDS-only drain: leaves global prefetch loads in flight (T4)
#define BAR_LGKM() asm volatile("s_waitcnt lgkmcnt(0)\ns_barrier" ::: "memory")

typedef __attribute__((ext_vector_type(8))) short bf16x8;
typedef __attribute__((ext_vector_type(4))) short bf16x4;
typedef __attribute__((ext_vector_type(2))) short bf16x2;
typedef __attribute__((ext_vector_type(4))) float f32x4;

__device__ __constant__ int c_atom_off[9] = {0,119,123,135,147,157,163,169,171};

static __device__ __forceinline__ float u16tof(unsigned short u) {
    return __uint_as_float(((unsigned int)u) << 16);
}
static __device__ __forceinline__ unsigned short ftobf(float f) {
    unsigned int u = __float_as_uint(f);
    unsigned int r = 0x7fffu + ((u >> 16) & 1u);
    return (unsigned short)((u + r) >> 16);
}
static __device__ __forceinline__ int geti(const void* p, int f64, long long i) {
    return f64 ? (int)((const long long*)p)[i] : ((const int*)p)[i];
}
static __device__ __forceinline__ f32x4 mfma16(bf16x8 a, bf16x8 b, f32x4 c) {
    return __builtin_amdgcn_mfma_f32_16x16x32_bf16(a, b, c, 0, 0, 0);
}

__global__ void k_detect(const int* __restrict__ ei, int* __restrict__ flag) {
    __shared__ int cnt;
    if (threadIdx.x == 0) cnt = 0;
    __syncthreads();
    int z = 0;
    for (int i = threadIdx.x; i < 1024; i += 256)
        if (ei[2 * i + 1] == 0) z++;
    atomicAdd(&cnt, z);
    __syncthreads();
    if (threadIdx.x == 0) *flag = (cnt > 512) ? 1 : 0;
}

__global__ void k_init(float* __restrict__ sc2, float* __restrict__ sh2) {
    const int c = blockIdx.x * 256 + threadIdx.x;
    if (c < EMB) { sc2[c] = 1.f; sh2[c] = 0.f; }
}

__global__ void k_encode(const void* __restrict__ x, const float* __restrict__ aemb,
                         float* __restrict__ h, const int* __restrict__ flag) {
    __shared__ int xi[4][9];
    const int ty = threadIdx.y, tx = threadIdx.x;
    const int n = blockIdx.x * 4 + ty;
    const int f64 = *flag;
    if (tx < 9) xi[ty][tx] = geti(x, f64, (long long)n * 9 + tx) + c_atom_off[tx];
    __syncthreads();
    if (tx < 75) {
        const int c = tx * 4;
        float s0 = 0.f, s1 = 0.f, s2 = 0.f, s3 = 0.f;
#pragma unroll
        for (int f = 0; f < 9; ++f) {
            const float4 v = *(const float4*)(aemb + (size_t)xi[ty][f] * EMB + c);
            s0 += v.x; s1 += v.y; s2 += v.z; s3 += v.w;
        }
        float4 o; o.x = s0; o.y = s1; o.z = s2; o.w = s3;
        *(float4*)(h + (size_t)n * EMB + c) = o;
    }
}

__global__ void k_deg(const void* __restrict__ ei, int* __restrict__ deg,
                      const int* __restrict__ flag) {
    const int e = blockIdx.x * 256 + threadIdx.x;
    if (e < EE) atomicAdd(&deg[geti(ei, *flag, (long long)EE + e)], 1);
}

__global__ void k_scanA(const int* __restrict__ deg, int* __restrict__ bsum) {
    __shared__ int red[256];
    const int b = blockIdx.x, t = threadIdx.x;
    const int base = b * 1024 + t * 4;
    int s = 0;
#pragma unroll
    for (int e = 0; e < 4; ++e) {
        const int i = base + e;
        if (i < NN) s += deg[i];
    }
    red[t] = s;
    __syncthreads();
    for (int off = 128; off > 0; off >>= 1) {
        if (t < off) red[t] += red[t + off];
        __syncthreads();
    }
    if (t == 0) bsum[b] = red[0];
}

__global__ void k_scanB(const int* __restrict__ bsum, int* __restrict__ bbase,
                        int* __restrict__ rowstart) {
    if (threadIdx.x == 0) {
        int run = 0;
        for (int b = 0; b < SCAN_NB; ++b) { bbase[b] = run; run += bsum[b]; }
        rowstart[NN] = run;
    }
}

__global__ void k_scanC(const int* __restrict__ deg, const int* __restrict__ bbase,
                        int* __restrict__ rowstart, int* __restrict__ cursor) {
    __shared__ int ts[256];
    const int b = blockIdx.x, t = threadIdx.x;
    const int base = b * 1024 + t * 4;
    int loc[4];
    int s = 0;
#pragma unroll
    for (int e = 0; e < 4; ++e) {
        const int i = base + e;
        loc[e] = (i < NN) ? deg[i] : 0;
        s += loc[e];
    }
    ts[t] = s;
    __syncthreads();
    for (int off = 1; off < 256; off <<= 1) {
        const int v = (t >= off) ? ts[t - off] : 0;
        __syncthreads();
        ts[t] += v;
        __syncthreads();
    }
    int run = bbase[b] + ts[t] - s;
#pragma unroll
    for (int e = 0; e < 4; ++e) {
        const int i = base + e;
        if (i < NN) { rowstart[i] = run; cursor[i] = run; run += loc[e]; }
    }
}

__global__ void k_scatter(const void* __restrict__ ei, const void* __restrict__ eattr,
                          int* __restrict__ cursor, int* __restrict__ elist,
                          const int* __restrict__ flag) {
    const int e = blockIdx.x * 256 + threadIdx.x;
    if (e >= EE) return;
    const int f64 = *flag;
    const int src = geti(ei, f64, e);
    const int dst = geti(ei, f64, (long long)EE + e);
    const int b0 = geti(eattr, f64, (long long)e * 3 + 0);
    const int b1 = geti(eattr, f64, (long long)e * 3 + 1);
    const int b2 = geti(eattr, f64, (long long)e * 3 + 2);
    const int pos = atomicAdd(&cursor[dst], 1);
    elist[pos] = src * 64 + b0 * 12 + b1 * 2 + b2;
}

__global__ void k_ebc(const float* __restrict__ bemb, float* __restrict__ ebc) {
    const int cb = blockIdx.x;
    const int tx = threadIdx.x;
    if (tx >= 75) return;
    const int b0 = cb / 12, b1 = (cb / 2) % 6, b2 = cb & 1;
    const int c = tx * 4;
    const float4 v0 = *(const float4*)(bemb + (size_t)b0 * EMB + c);
    const float4 v1 = *(const float4*)(bemb + (size_t)(5 + b1) * EMB + c);
    const float4 v2 = *(const float4*)(bemb + (size_t)(11 + b2) * EMB + c);
    float4 o; o.x = v0.x + v1.x + v2.x; o.y = v0.y + v1.y + v2.y;
    o.z = v0.z + v1.z + v2.z; o.w = v0.w + v1.w + v2.w;
    *(float4*)(ebc + (size_t)cb * EMB + c) = o;
}

// ---- gather: 4 nodes/block, batched edge loads, fused BN2+relu ----
__global__ void k_gather(const int* __restrict__ rowstart, const int* __restrict__ elist,
                         const float* __restrict__ ebc,
                         const float* __restrict__ h, float* __restrict__ z,
                         const float* __restrict__ sc, const float* __restrict__ sh,
                         int dorelu) {
    const int ty = threadIdx.y, tx = threadIdx.x;
    const int n = blockIdx.x * 4 + ty;
    if (tx >= 75) return;
    const int c = tx * 4;
    const float4 s4 = *(const float4*)(sc + c);
    const float4 h4 = *(const float4*)(sh + c);
    const int s = rowstart[n], e = rowstart[n + 1];
    float4 acc;
    {
        float4 v = *(const float4*)(h + (size_t)n * EMB + c);
        v.x = fmaf(v.x, s4.x, h4.x); v.y = fmaf(v.y, s4.y, h4.y);
        v.z = fmaf(v.z, s4.z, h4.z); v.w = fmaf(v.w, s4.w, h4.w);
        if (dorelu) {
            v.x = fmaxf(v.x, 0.f); v.y = fmaxf(v.y, 0.f);
            v.z = fmaxf(v.z, 0.f); v.w = fmaxf(v.w, 0.f);
        }
        acc = v;
    }
    for (int j = s; j < e; j += 4) {
        const int m = e - j;
        int pk[4];
#pragma unroll
        for (int d = 0; d < 4; ++d) pk[d] = (d < m) ? elist[j + d] : 0;
        float4 hv[4], ev[4];
#pragma unroll
        for (int d = 0; d < 4; ++d) {
            if (d < m) {
                const int src = pk[d] >> 6, cb = pk[d] & 63;
                hv[d] = *(const float4*)(h + (size_t)src * EMB + c);
                ev[d] = *(const float4*)(ebc + (size_t)cb * EMB + c);
            }
        }
#pragma unroll
        for (int d = 0; d < 4; ++d) {
            if (d < m) {
                float4 t = hv[d];
                t.x = fmaf(t.x, s4.x, h4.x); t.y = fmaf(t.y, s4.y, h4.y);
                t.z = fmaf(t.z, s4.z, h4.z); t.w = fmaf(t.w, s4.w, h4.w);
                if (dorelu) {
                    t.x = fmaxf(t.x, 0.f); t.y = fmaxf(t.y, 0.f);
                    t.z = fmaxf(t.z, 0.f); t.w = fmaxf(t.w, 0.f);
                }
                acc.x += fmaxf(t.x + ev[d].x, 0.f);
                acc.y += fmaxf(t.y + ev[d].y, 0.f);
                acc.z += fmaxf(t.z + ev[d].z, 0.f);
                acc.w += fmaxf(t.w + ev[d].w, 0.f);
            }
        }
    }
    *(float4*)(z + (size_t)n * EMB + c) = acc;
}

__global__ void k_wconv1(const float* __restrict__ W, unsigned short* __restrict__ hi,
                         unsigned short* __restrict__ lo) {
    const int idx = blockIdx.x * 256 + threadIdx.x;
    if (idx >= 10 * 40 * 64 * 8) return;
    const int e = idx & 7;
    const int lane = (idx >> 3) & 63;
    const int nt = (idx >> 9) % 40;
    const int kt = idx / 20480;
    const int r = lane & 15, g = lane >> 4;
    const int col = nt * 16 + r;
    const int k = kt * 32 + g * 8 + e;
    const float w = (col < EMB2 && k < EMB) ? W[(size_t)k * EMB2 + col] : 0.f;
    const unsigned short h = ftobf(w);
    hi[idx] = h;
    lo[idx] = ftobf(w - u16tof(h));
}
__global__ void k_wconv2(const float* __restrict__ W, unsigned short* __restrict__ hi,
                         unsigned short* __restrict__ lo) {
    const int idx = blockIdx.x * 256 + threadIdx.x;
    if (idx >= 19 * 20 * 64 * 8) return;
    const int e = idx & 7;
    const int lane = (idx >> 3) & 63;
    const int nt = (idx >> 9) % 20;
    const int kt = idx / 10240;
    const int r = lane & 15, g = lane >> 4;
    const int col = nt * 16 + r;
    const int k = kt * 32 + g * 8 + e;
    const float w = (col < EMB && k < EMB2) ? W[(size_t)k * EMB + col] : 0.f;
    const unsigned short h = ftobf(w);
    hi[idx] = h;
    lo[idx] = ftobf(w - u16tof(h));
}

// ---- MFMA GEMM1: 32-row blocks, 512 thr; 2-deep prefetch + weakened barrier ----
// z1a (cols<300) -> Q in-place, z1b (300-599) -> P. Fused BN1 partial stats (16-way spread).
__global__ __launch_bounds__(512) void k_mfma1(
    float* __restrict__ P, float* Q,
    const unsigned short* __restrict__ whi, const unsigned short* __restrict__ wlo,
    float* __restrict__ sum1p, float* __restrict__ ss1p)
{
    __shared__ __align__(16) short AsH[3][1024];
    __shared__ __align__(16) short AsL[3][1024];
    const int tid = threadIdx.x;
    const int lane = tid & 63;
    const int wn = tid >> 6;
    const int g = lane >> 4, r = lane & 15;
    const int row0 = blockIdx.x * 32;
    const int cp = (blockIdx.x & (NCOPY - 1)) * EMB2;
    const int se2 = (tid & 3) * 2, str = (tid >> 2) & 15, stg = (tid >> 6) & 3, srg = tid >> 8;
    const int srow = row0 + srg * 16 + str;
    const int sldo = tid * 2;
    f32x4 acc[2][5];
#pragma unroll
    for (int rg = 0; rg < 2; ++rg)
#pragma unroll
        for (int t = 0; t < 5; ++t) acc[rg][t] = (f32x4){0.f, 0.f, 0.f, 0.f};

    auto loadA = [&](int kt, float2& v) {
        const int cc = kt * 32 + stg * 8 + se2;
        v = (float2){0.f, 0.f};
        if (cc + 1 < EMB) v = *(const float2*)(Q + (size_t)srow * EMB + cc);
    };
    auto writeA = [&](int b, float2 v) {
        bf16x2 h2, l2;
        const unsigned short hx = ftobf(v.x);
        h2[0] = (short)hx; l2[0] = (short)ftobf(v.x - u16tof(hx));
        const unsigned short hy = ftobf(v.y);
        h2[1] = (short)hy; l2[1] = (short)ftobf(v.y - u16tof(hy));
        *(bf16x2*)(&AsH[b][sldo]) = h2;
        *(bf16x2*)(&AsL[b][sldo]) = l2;
    };

    {
        float2 v0;
        loadA(0, v0);
        writeA(0, v0);
    }
    float2 vpend;
    loadA(1, vpend);      // stays in flight across the weakened barrier
    BAR_LGKM();

    for (int kt = 0; kt < 10; ++kt) {
        const int cur = kt - (kt / 3) * 3;          // kt % 3
        float2 vnext = {0.f, 0.f};
        if (kt + 2 < 10) loadA(kt + 2, vnext);      // 2-deep prefetch
        bf16x8 ah[2], al[2];
#pragma unroll
        for (int rg = 0; rg < 2; ++rg) {
            ah[rg] = *(const bf16x8*)(&AsH[cur][rg * 512 + lane * 8]);
            al[rg] = *(const bf16x8*)(&AsL[cur][rg * 512 + lane * 8]);
        }
#pragma unroll
        for (int t = 0; t < 5; ++t) {
            const size_t wb = ((size_t)(kt * 40 + wn + t * 8) * 64 + lane) * 8;
            const bf16x8 bh = *(const bf16x8*)(whi + wb);
            const bf16x8 bl = *(const bf16x8*)(wlo + wb);
#pragma unroll
            for (int rg = 0; rg < 2; ++rg) {
                acc[rg][t] = mfma16(al[rg], bh, acc[rg][t]);
                acc[rg][t] = mfma16(ah[rg], bl, acc[rg][t]);
                acc[rg][t] = mfma16(ah[rg], bh, acc[rg][t]);
            }
        }
        if (kt + 1 < 10) {
            const int nb = (kt + 1) - ((kt + 1) / 3) * 3;
            writeA(nb, vpend);
        }
        vpend = vnext;
        BAR_LGKM();
    }
    // epilogue: C writes + per-column partial stats (32 rows of this block)
#pragma unroll
    for (int t = 0; t < 5; ++t) {
        const int col = (wn + t * 8) * 16 + r;
        float s = 0.f, q = 0.f;
#pragma unroll
        for (int rg = 0; rg < 2; ++rg) {
            const int orow = row0 + rg * 16 + g * 4;
#pragma unroll
            for (int j = 0; j < 4; ++j) {
                const float val = acc[rg][t][j];
                s += val; q += val * val;
                if (col < EMB)       Q[(size_t)(orow + j) * EMB + col] = val;
                else if (col < EMB2) P[(size_t)(orow + j) * EMB + (col - EMB)] = val;
            }
        }
        s += __shfl_xor(s, 16); s += __shfl_xor(s, 32);
        q += __shfl_xor(q, 16); q += __shfl_xor(q, 32);
        if (g == 0 && col < EMB2) {
            atomicAdd(&sum1p[cp + col], s);
            atomicAdd(&ss1p[cp + col], q);
        }
    }
}

// ---- MFMA GEMM2: 64-row blocks, 512 thr (8 waves = 2 row-halves x 4 col-waves) ----
// Halves per-block weight re-reads from L2 and doubles per-block wave parallelism.
// 2-deep prefetch + weakened barrier; fused BN2 partial stats (16-way spread).
__global__ __launch_bounds__(512) void k_mfma2(
    float* P, const float* __restrict__ Qa,
    const float* __restrict__ sc, const float* __restrict__ sh,
    const unsigned short* __restrict__ whi, const unsigned short* __restrict__ wlo,
    float* __restrict__ sum2p, float* __restrict__ ss2p)
{
    __shared__ __align__(16) short AsH[3][2048];
    __shared__ __align__(16) short AsL[3][2048];
    const int tid = threadIdx.x;
    const int lane = tid & 63;
    const int wn = tid >> 6;            // 0..7
    const int wr = wn >> 2;             // row-half 0..1
    const int wc = wn & 3;              // col-wave 0..3
    const int g = lane >> 4, r = lane & 15;
    const int row0 = blockIdx.x * 64;
    const int cp = (blockIdx.x & (NCOPY - 1)) * EMB;
    // staging: 512 thr x float4 = 64 rows x 32 k
    const int se4 = (tid & 1) * 4, str = (tid >> 1) & 15, stg = (tid >> 5) & 3, srg = tid >> 7;
    const int srow = row0 + srg * 16 + str;
    const int sldo = tid * 4;
    f32x4 acc[2][5];
#pragma unroll
    for (int rg = 0; rg < 2; ++rg)
#pragma unroll
        for (int t = 0; t < 5; ++t) acc[rg][t] = (f32x4){0.f, 0.f, 0.f, 0.f};

    auto loadA = [&](int kt, float4& v) {
        const int cc = kt * 32 + stg * 8 + se4;
        v = (float4){0.f, 0.f, 0.f, 0.f};
        if (srow < NN) {
            if (cc + 3 < EMB)       v = *(const float4*)(Qa + (size_t)srow * EMB + cc);
            else if (cc + 3 < EMB2) v = *(const float4*)(P + (size_t)srow * EMB + (cc - EMB));
        }
    };
    auto writeA = [&](int kt, int b, float4 v) {
        const int cc = kt * 32 + stg * 8 + se4;
        if (cc + 3 < EMB2) {
            const float4 s4 = *(const float4*)(sc + cc);
            const float4 h4 = *(const float4*)(sh + cc);
            v.x = fmaxf(fmaf(v.x, s4.x, h4.x), 0.f);
            v.y = fmaxf(fmaf(v.y, s4.y, h4.y), 0.f);
            v.z = fmaxf(fmaf(v.z, s4.z, h4.z), 0.f);
            v.w = fmaxf(fmaf(v.w, s4.w, h4.w), 0.f);
        } else {
            v = (float4){0.f, 0.f, 0.f, 0.f};
        }
        bf16x4 h4v, l4v;
        const float vv[4] = {v.x, v.y, v.z, v.w};
#pragma unroll
        for (int e = 0; e < 4; ++e) {
            const unsigned short hh = ftobf(vv[e]);
            h4v[e] = (short)hh;
            l4v[e] = (short)ftobf(vv[e] - u16tof(hh));
        }
        *(bf16x4*)(&AsH[b][sldo]) = h4v;
        *(bf16x4*)(&AsL[b][sldo]) = l4v;
    };

    {
        float4 v0;
        loadA(0, v0);
        writeA(0, 0, v0);
    }
    float4 vpend;
    loadA(1, vpend);
    BAR_LGKM();

    for (int kt = 0; kt < 19; ++kt) {
        const int cur = kt - (kt / 3) * 3;
        float4 vnext = {0.f, 0.f, 0.f, 0.f};
        if (kt + 2 < 19) loadA(kt + 2, vnext);
        bf16x8 ah[2], al[2];
#pragma unroll
        for (int rg = 0; rg < 2; ++rg) {
            const int reg = wr * 2 + rg;   // 16-row region 0..3
            ah[rg] = *(const bf16x8*)(&AsH[cur][reg * 512 + lane * 8]);
            al[rg] = *(const bf16x8*)(&AsL[cur][reg * 512 + lane * 8]);
        }
#pragma unroll
        for (int t = 0; t < 5; ++t) {
            const size_t wb = ((size_t)(kt * 20 + wc + t * 4) * 64 + lane) * 8;
            const bf16x8 bh = *(const bf16x8*)(whi + wb);
            const bf16x8 bl = *(const bf16x8*)(wlo + wb);
#pragma unroll
            for (int rg = 0; rg < 2; ++rg) {
                acc[rg][t] = mfma16(al[rg], bh, acc[rg][t]);
                acc[rg][t] = mfma16(ah[rg], bl, acc[rg][t]);
                acc[rg][t] = mfma16(ah[rg], bh, acc[rg][t]);
            }
        }
        if (kt + 1 < 19) {
            const int nb = (kt + 1) - ((kt + 1) / 3) * 3;
            writeA(kt + 1, nb, vpend);
        }
        vpend = vnext;
        BAR_LGKM();
    }
    // epilogue: C writes + per-column partial stats (this wave's 32-row half)
#pragma unroll
    for (int t = 0; t < 5; ++t) {
        const int col = (wc + t * 4) * 16 + r;
        float s = 0.f, q = 0.f;
#pragma unroll
        for (int rg = 0; rg < 2; ++rg) {
            const int orow = row0 + (wr * 2 + rg) * 16 + g * 4;
#pragma unroll
            for (int j = 0; j < 4; ++j) {
                const float val = acc[rg][t][j];
                s += val; q += val * val;
                if (col < EMB && orow + j < NN)
                    P[(size_t)(orow + j) * EMB + col] = val;
            }
        }
        s += __shfl_xor(s, 16); s += __shfl_xor(s, 32);
        q += __shfl_xor(q, 16); q += __shfl_xor(q, 32);
        if (g == 0 && col < EMB) {
            atomicAdd(&sum2p[cp + col], s);
            atomicAdd(&ss2p[cp + col], q);
        }
    }
}

// ---- reduce NCOPY partial copies + compute BN scale/shift ----
__global__ void k_scale16(const float* __restrict__ psum, const float* __restrict__ pss,
                          const float* __restrict__ g, const float* __restrict__ b,
                          float* __restrict__ scale, float* __restrict__ shift, int C) {
    const int c = blockIdx.x * 256 + threadIdx.x;
    if (c >= C) return;
    float s = 0.f, q = 0.f;
#pragma unroll
    for (int k = 0; k < NCOPY; ++k) {
        s += psum[k * C + c];
        q += pss[k * C + c];
    }
    const float invN = 1.0f / (float)NN;
    const float mean = s * invN;
    const float var = q * invN - mean * mean;
    const float sc = g[c] * rsqrtf(var + BN_EPS);
    scale[c] = sc;
    shift[c] = b[c] - mean * sc;
}

__global__ void k_poolg(const void* __restrict__ batch, const float* __restrict__ h,
                        float* __restrict__ out, const int* __restrict__ flag,
                        const float* __restrict__ sc, const float* __restrict__ sh) {
    __shared__ float red[4][EMB];
    const int g = blockIdx.x;
    const int f64 = *flag;
    int lo = 0, hi = NN;
    while (lo < hi) { int mid = (lo + hi) >> 1; if (geti(batch, f64, mid) < g) lo = mid + 1; else hi = mid; }
    const int s = lo;
    hi = NN;
    while (lo < hi) { int mid = (lo + hi) >> 1; if (geti(batch, f64, mid) < g + 1) lo = mid + 1; else hi = mid; }
    const int e = lo;
    const int tx = threadIdx.x, ty = threadIdx.y;
    if (tx < 75) {
        const int c = tx * 4;
        const float4 s4 = *(const float4*)(sc + c);
        const float4 h4 = *(const float4*)(sh + c);
        float4 acc; acc.x = acc.y = acc.z = acc.w = 0.f;
        int cntr = 0;
        for (int r = s + ty; r < e; r += 4) {
            const float4 v = *(const float4*)(h + (size_t)r * EMB + c);
            acc.x += v.x; acc.y += v.y; acc.z += v.z; acc.w += v.w;
            cntr++;
        }
        acc.x = fmaf(acc.x, s4.x, cntr * h4.x);
        acc.y = fmaf(acc.y, s4.y, cntr * h4.y);
        acc.z = fmaf(acc.z, s4.z, cntr * h4.z);
        acc.w = fmaf(acc.w, s4.w, cntr * h4.w);
        *(float4*)(&red[ty][c]) = acc;
    }
    __syncthreads();
    if (ty == 0 && tx < 75) {
        const int c = tx * 4;
        float4 o;
        o.x = red[0][c + 0] + red[1][c + 0] + red[2][c + 0] + red[3][c + 0];
        o.y = red[0][c + 1] + red[1][c + 1] + red[2][c + 1] + red[3][c + 1];
        o.z = red[0][c + 2] + red[1][c + 2] + red[2][c + 2] + red[3][c + 2];
        o.w = red[0][c + 3] + red[1][c + 3] + red[2][c + 3] + red[3][c + 3];
        *(float4*)(out + (size_t)g * EMB + c) = o;
    }
}

extern "C" void kernel_launch(void* const* d_in, const int* in_sizes, int n_in,
                              void* d_out, int out_size, void* d_ws, size_t ws_size,
                              hipStream_t stream) {
    const void* x     = d_in[0];
    const void* ei    = d_in[1];
    const void* eattr = d_in[2];
    const void* batch = d_in[3];
    const float* aemb = (const float*)d_in[4];
    const float* bemb = (const float*)d_in[5];
    const float* W1   = (const float*)d_in[6];
    const float* g1   = (const float*)d_in[8];
    const float* bt1  = (const float*)d_in[9];
    const float* W2   = (const float*)d_in[10];
    const float* g2   = (const float*)d_in[12];
    const float* bt2  = (const float*)d_in[13];

    char* ws = (char*)d_ws;
    const bool pre2 = (ws_size >= 2ull * BUF_BYTES + 2888640ull + 5ull * WSET);

    float* P = (float*)(ws);
    float* Q = (float*)(ws + BUF_BYTES);
    char* aux = ws + 2ull * BUF_BYTES;

    float* st = (float*)(aux);
    float* sc1  = st + 1800;  float* sh1 = st + 2400;
    float* sc2  = st + 3000;  float* sh2 = st + 3300;
    int* flag     = (int*)(aux + 16384);
    int* deg      = (int*)(aux + 16384 + 64);
    int* rowstart = (int*)(aux + 16384 + 64 + 400064);
    int* cursor   = (int*)(aux + 16384 + 64 + 800128);
    int* elist    = (int*)(aux + 16384 + 64 + 1200192);
    float* ebc    = (float*)(aux + 16384 + 64 + 2800192);
    int* bsum     = (int*)(aux + 2872192);
    int* bbase    = (int*)(aux + 2872192 + 512);
    char* wbase   = aux + 2888640;
    // BN partial copies reuse the (dead-after-setup) cursor region: 28800 floats = 115.2 KB < 400 KB
    float* parts  = (float*)cursor;
    float* sum1p  = parts;            // 16*600
    float* ss1p   = parts + 9600;     // 16*600
    float* sum2p  = parts + 19200;    // 16*300
    float* ss2p   = parts + 24000;    // 16*300

    const dim3 blk80x4(80, 4);

    k_detect<<<1, 256, 0, stream>>>((const int*)ei, flag);
    k_init<<<2, 256, 0, stream>>>(sc2, sh2);

    (void)hipMemsetAsync(deg, 0, NN * sizeof(int), stream);
    k_deg<<<(EE + 255) / 256, 256, 0, stream>>>(ei, deg, flag);
    k_scanA<<<SCAN_NB, 256, 0, stream>>>(deg, bsum);
    k_scanB<<<1, 64, 0, stream>>>(bsum, bbase, rowstart);
    k_scanC<<<SCAN_NB, 256, 0, stream>>>(deg, bbase, rowstart, cursor);
    k_scatter<<<(EE + 255) / 256, 256, 0, stream>>>(ei, eattr, cursor, elist, flag);
    k_ebc<<<60, 80, 0, stream>>>(bemb, ebc);

    if (pre2) {
        for (int i = 0; i < LL; ++i) {
            char* wb = wbase + (size_t)i * WSET;
            k_wconv1<<<(204800 + 255) / 256, 256, 0, stream>>>(
                W1 + (size_t)i * EMB * EMB2,
                (unsigned short*)wb, (unsigned short*)(wb + 409600));
            k_wconv2<<<(194560 + 255) / 256, 256, 0, stream>>>(
                W2 + (size_t)i * EMB2 * EMB,
                (unsigned short*)(wb + 819200), (unsigned short*)(wb + 819200 + 389120));
        }
    }

    k_encode<<<NN / 4, blk80x4, 0, stream>>>(x, aemb, P, flag);

    for (int i = 0; i < LL; ++i) {
        char* wb = wbase + (pre2 ? (size_t)i * WSET : 0ull);
        unsigned short* wt1hi = (unsigned short*)wb;
        unsigned short* wt1lo = (unsigned short*)(wb + 409600);
        unsigned short* wt2hi = (unsigned short*)(wb + 819200);
        unsigned short* wt2lo = (unsigned short*)(wb + 819200 + 389120);

        if (!pre2) {
            k_wconv1<<<(204800 + 255) / 256, 256, 0, stream>>>(
                W1 + (size_t)i * EMB * EMB2, wt1hi, wt1lo);
            k_wconv2<<<(194560 + 255) / 256, 256, 0, stream>>>(
                W2 + (size_t)i * EMB2 * EMB, wt2hi, wt2lo);
        }
        (void)hipMemsetAsync(parts, 0, 28800 * sizeof(float), stream);

        k_gather<<<NN / 4, blk80x4, 0, stream>>>(rowstart, elist, ebc, P, Q,
                                                 sc2, sh2, (i > 0) ? 1 : 0);

        // z1 = z @ W1 (+ fused BN1 partial stats): z1a -> Q in-place, z1b -> P
        k_mfma1<<<NN / 32, 512, 0, stream>>>(P, Q, wt1hi, wt1lo, sum1p, ss1p);
        k_scale16<<<3, 256, 0, stream>>>(sum1p, ss1p, g1 + (size_t)i * EMB2,
                                         bt1 + (size_t)i * EMB2, sc1, sh1, EMB2);

        // h_pre = relu(BN1([Q|P])) @ W2 -> P in-place (+ fused BN2 partial stats)
        k_mfma2<<<(NN + 63) / 64, 512, 0, stream>>>(P, Q, sc1, sh1, wt2hi, wt2lo, sum2p, ss2p);
        k_scale16<<<2, 256, 0, stream>>>(sum2p, ss2p, g2 + (size_t)i * EMB,
                                         bt2 + (size_t)i * EMB, sc2, sh2, EMB);
    }

    k_poolg<<<GG, blk80x4, 0, stream>>>(batch, P, (float*)d_out, flag, sc2, sh2);
}